// Round 1
// baseline (674.752 us; speedup 1.0000x reference)
//
#include <hip/hip_runtime.h>

#define TT   524288
#define CHUNK 512
#define NCH  (TT / CHUNK)      // 1024 chunks
#define RSUB 32                // subtile rows
#define NSUB (CHUNK / RSUB)    // 16 subtiles per chunk

// LDS row pads (floats)
#define W1P 132                // 128 + 4, keeps float4 alignment, breaks pow2 stride
#define XP  65
#define ABP 68
#define ZP  68
#define W2P 36

__device__ __forceinline__ float sigmoidf_fast(float v) {
    return 1.0f / (1.0f + __expf(-v));
}

// EMIT=false: compute per-chunk affine composition (A,B) per channel.
// EMIT=true : given chunk carry, recompute a,b, scan z, fuse out = z@W2+B2.
template <bool EMIT>
__global__ __launch_bounds__(256, 2)
void deductron_phase(const float* __restrict__ x, const float* __restrict__ W1,
                     const float* __restrict__ B1, const float* __restrict__ W2,
                     const float* __restrict__ B2, const float* __restrict__ carry,
                     float* __restrict__ Aout, float* __restrict__ Bout,
                     float* __restrict__ out)
{
    __shared__ __align__(16) float W1s[64 * W1P];
    __shared__ float B1s[128];
    __shared__ float Xs[RSUB * XP];
    __shared__ __align__(16) float as[RSUB * ABP];
    __shared__ __align__(16) float bs[RSUB * ABP];
    __shared__ float Zs[RSUB * ZP];
    __shared__ __align__(16) float W2s[64 * W2P];
    __shared__ float B2s[32];

    const int tid = threadIdx.x;
    const int c   = blockIdx.x;

    // ---- stage weights ----
    for (int i = tid; i < 64 * 128; i += 256) {
        int k = i >> 7, j = i & 127;
        W1s[k * W1P + j] = W1[i];
    }
    if (tid < 128) B1s[tid] = B1[tid];
    if (EMIT) {
        for (int i = tid; i < 64 * 32; i += 256) {
            int k = i >> 5, j = i & 31;
            W2s[k * W2P + j] = W2[i];
        }
        if (tid < 32) B2s[tid] = B2[tid];
    }
    __syncthreads();

    // GEMM thread tiling: 2 rows x (4 left cols + 4 right cols) per thread
    const int ty = tid >> 4;        // 0..15
    const int tx = tid & 15;        // 0..15
    const int r0 = ty * 2;          // rows r0, r0+1 of subtile
    const int jL = tx * 4;          // left cols  (channel  0..63)
    const int jR = 64 + tx * 4;     // right cols (channel 64..127)

    // scan state: wave 0, lane = channel
    float sA = 1.0f, sB = 0.0f;     // !EMIT: running composition
    float u  = 0.0f;                // EMIT: running z
    if (EMIT) {
        if (tid < 64) u = carry[c * 64 + tid];
    }

    const int base = c * CHUNK;
    for (int s = 0; s < NSUB; ++s) {
        const int row0 = base + s * RSUB;

        // ---- stage X subtile (RSUB x 64), perfectly coalesced ----
        for (int i = tid; i < RSUB * 64; i += 256) {
            int r = i >> 6, k = i & 63;
            Xs[r * XP + k] = x[(size_t)row0 * 64 + i];
        }
        __syncthreads();

        // ---- h = sigmoid(X @ W1 + B1): register-tiled fp32 GEMM ----
        float accL[2][4], accR[2][4];
        #pragma unroll
        for (int i = 0; i < 4; ++i) {
            accL[0][i] = B1s[jL + i]; accL[1][i] = B1s[jL + i];
            accR[0][i] = B1s[jR + i]; accR[1][i] = B1s[jR + i];
        }
        #pragma unroll 4
        for (int k = 0; k < 64; ++k) {
            const float x0 = Xs[r0 * XP + k];
            const float x1 = Xs[(r0 + 1) * XP + k];
            const float4 wl = *(const float4*)&W1s[k * W1P + jL];
            const float4 wr = *(const float4*)&W1s[k * W1P + jR];
            accL[0][0] += x0 * wl.x; accL[0][1] += x0 * wl.y;
            accL[0][2] += x0 * wl.z; accL[0][3] += x0 * wl.w;
            accL[1][0] += x1 * wl.x; accL[1][1] += x1 * wl.y;
            accL[1][2] += x1 * wl.z; accL[1][3] += x1 * wl.w;
            accR[0][0] += x0 * wr.x; accR[0][1] += x0 * wr.y;
            accR[0][2] += x0 * wr.z; accR[0][3] += x0 * wr.w;
            accR[1][0] += x1 * wr.x; accR[1][1] += x1 * wr.y;
            accR[1][2] += x1 * wr.z; accR[1][3] += x1 * wr.w;
        }

        // ---- sigmoid, a = l*r, b = 1-l; write to LDS (channel = left col) ----
        #pragma unroll
        for (int r = 0; r < 2; ++r) {
            float4 av, bv;
            float hl, hr;
            hl = sigmoidf_fast(accL[r][0]); hr = sigmoidf_fast(accR[r][0]);
            av.x = hl * hr; bv.x = 1.0f - hl;
            hl = sigmoidf_fast(accL[r][1]); hr = sigmoidf_fast(accR[r][1]);
            av.y = hl * hr; bv.y = 1.0f - hl;
            hl = sigmoidf_fast(accL[r][2]); hr = sigmoidf_fast(accR[r][2]);
            av.z = hl * hr; bv.z = 1.0f - hl;
            hl = sigmoidf_fast(accL[r][3]); hr = sigmoidf_fast(accR[r][3]);
            av.w = hl * hr; bv.w = 1.0f - hl;
            *(float4*)&as[(r0 + r) * ABP + jL] = av;
            *(float4*)&bs[(r0 + r) * ABP + jL] = bv;
        }
        __syncthreads();

        // ---- sequential scan over subtile rows (wave 0, lane = channel) ----
        if (tid < 64) {
            #pragma unroll
            for (int t = 0; t < RSUB; ++t) {
                const float at = as[t * ABP + tid];
                const float bt = bs[t * ABP + tid];
                if (EMIT) {
                    Zs[t * ZP + tid] = u;          // z[row] BEFORE applying row's map
                    u = fmaf(at, u, bt);
                } else {
                    sB = fmaf(at, sB, bt);         // compose (at,bt) after (sA,sB)
                    sA = at * sA;
                }
            }
        }
        __syncthreads();

        if (EMIT) {
            // ---- out = Z @ W2 + B2, fused store ----
            const int orow = tid >> 3;             // 0..31
            const int oj   = (tid & 7) * 4;        // 0..28
            float acc[4];
            #pragma unroll
            for (int i = 0; i < 4; ++i) acc[i] = B2s[oj + i];
            #pragma unroll 4
            for (int k = 0; k < 64; ++k) {
                const float z = Zs[orow * ZP + k];
                const float4 w = *(const float4*)&W2s[k * W2P + oj];
                acc[0] += z * w.x; acc[1] += z * w.y;
                acc[2] += z * w.z; acc[3] += z * w.w;
            }
            float4 o4 = make_float4(acc[0], acc[1], acc[2], acc[3]);
            *(float4*)&out[(size_t)(row0 + orow) * 32 + oj] = o4;
            __syncthreads();   // Zs fully consumed before next subtile's scan writes
        }
    }

    if (!EMIT && tid < 64) {
        Aout[c * 64 + tid] = sA;
        Bout[c * 64 + tid] = sB;
    }
}

// Sequential scan over chunk carries: carry[c] = z[c*CHUNK]
__global__ void carry_scan(const float* __restrict__ Aar, const float* __restrict__ Bar,
                           float* __restrict__ carry)
{
    const int ch = threadIdx.x;   // 64 threads = 64 channels
    float u = 0.0f;
    carry[ch] = 0.0f;
    #pragma unroll 8
    for (int c = 1; c < NCH; ++c) {
        const float A  = Aar[(c - 1) * 64 + ch];
        const float Bv = Bar[(c - 1) * 64 + ch];
        u = fmaf(A, u, Bv);
        carry[c * 64 + ch] = u;
    }
}

extern "C" void kernel_launch(void* const* d_in, const int* in_sizes, int n_in,
                              void* d_out, int out_size, void* d_ws, size_t ws_size,
                              hipStream_t stream)
{
    const float* x  = (const float*)d_in[0];
    const float* W1 = (const float*)d_in[1];
    const float* B1 = (const float*)d_in[2];
    const float* W2 = (const float*)d_in[3];
    const float* B2 = (const float*)d_in[4];
    float* out = (float*)d_out;

    float* Aar   = (float*)d_ws;           // NCH*64 floats
    float* Bar   = Aar + NCH * 64;         // NCH*64 floats
    float* carry = Bar + NCH * 64;         // NCH*64 floats  (total 768 KB)

    deductron_phase<false><<<NCH, 256, 0, stream>>>(x, W1, B1, W2, B2, nullptr,
                                                    Aar, Bar, nullptr);
    carry_scan<<<1, 64, 0, stream>>>(Aar, Bar, carry);
    deductron_phase<true><<<NCH, 256, 0, stream>>>(x, W1, B1, W2, B2, carry,
                                                   nullptr, nullptr, out);
}

// Round 2
// 507.020 us; speedup vs baseline: 1.3308x; 1.3308x over previous
//
#include <hip/hip_runtime.h>
#include <hip/hip_fp16.h>

#define TT    524288
#define CHUNK 512
#define NCH   (TT / CHUNK)     // 1024 chunks
#define RSUB  32               // phase-1 subtile rows
#define NSUB  (CHUNK / RSUB)   // 16
#define R2    64               // phase-2 subtile rows
#define NS2   (CHUNK / R2)     // 8

// LDS pads (floats)
#define W1P 132
#define XP  65
#define ABP 68
#define ZP  65
#define W2P 36
#define SEGP 66

__device__ __forceinline__ float sigmoidf_fast(float v) {
    return 1.0f / (1.0f + __expf(-v));
}

// ============================================================================
// Phase 1: h = sigmoid(x@W1+B1) -> a,b; store a,b to global as half2;
//          compute per-chunk affine composition (A,B) via parallel segments.
// ============================================================================
__global__ __launch_bounds__(256, 2)
void phase1(const float* __restrict__ x, const float* __restrict__ W1,
            const float* __restrict__ B1, __half2* __restrict__ ab,
            float* __restrict__ Aout, float* __restrict__ Bout)
{
    __shared__ __align__(16) float W1s[64 * W1P];
    __shared__ float B1s[128];
    __shared__ float Xs[RSUB * XP];
    __shared__ __align__(16) float as_[RSUB * ABP];
    __shared__ __align__(16) float bs_[RSUB * ABP];
    __shared__ float segA[4 * SEGP];
    __shared__ float segB[4 * SEGP];

    const int tid = threadIdx.x;
    const int c   = blockIdx.x;

    for (int i = tid; i < 64 * 128; i += 256) {
        int k = i >> 7, j = i & 127;
        W1s[k * W1P + j] = W1[i];
    }
    if (tid < 128) B1s[tid] = B1[tid];
    __syncthreads();

    const int ty = tid >> 4, tx = tid & 15;
    const int r0 = ty * 2;
    const int jL = tx * 4;
    const int jR = 64 + tx * 4;
    const int ch = tid & 63, seg = tid >> 6;   // seg wave-uniform

    float sA = 1.0f, sB = 0.0f;                // running chunk map (tid<64)

    const size_t base = (size_t)c * CHUNK;
    for (int s = 0; s < NSUB; ++s) {
        const size_t row0 = base + (size_t)s * RSUB;

        for (int i = tid; i < RSUB * 64; i += 256) {
            int r = i >> 6, k = i & 63;
            Xs[r * XP + k] = x[row0 * 64 + i];
        }
        __syncthreads();   // B1

        float accL[2][4], accR[2][4];
        #pragma unroll
        for (int i = 0; i < 4; ++i) {
            accL[0][i] = B1s[jL + i]; accL[1][i] = B1s[jL + i];
            accR[0][i] = B1s[jR + i]; accR[1][i] = B1s[jR + i];
        }
        #pragma unroll 4
        for (int k = 0; k < 64; ++k) {
            const float x0 = Xs[r0 * XP + k];
            const float x1 = Xs[(r0 + 1) * XP + k];
            const float4 wl = *(const float4*)&W1s[k * W1P + jL];
            const float4 wr = *(const float4*)&W1s[k * W1P + jR];
            accL[0][0] += x0 * wl.x; accL[0][1] += x0 * wl.y;
            accL[0][2] += x0 * wl.z; accL[0][3] += x0 * wl.w;
            accL[1][0] += x1 * wl.x; accL[1][1] += x1 * wl.y;
            accL[1][2] += x1 * wl.z; accL[1][3] += x1 * wl.w;
            accR[0][0] += x0 * wr.x; accR[0][1] += x0 * wr.y;
            accR[0][2] += x0 * wr.z; accR[0][3] += x0 * wr.w;
            accR[1][0] += x1 * wr.x; accR[1][1] += x1 * wr.y;
            accR[1][2] += x1 * wr.z; accR[1][3] += x1 * wr.w;
        }

        #pragma unroll
        for (int r = 0; r < 2; ++r) {
            float4 av, bv;
            float hl, hr;
            hl = sigmoidf_fast(accL[r][0]); hr = sigmoidf_fast(accR[r][0]);
            av.x = hl * hr; bv.x = 1.0f - hl;
            hl = sigmoidf_fast(accL[r][1]); hr = sigmoidf_fast(accR[r][1]);
            av.y = hl * hr; bv.y = 1.0f - hl;
            hl = sigmoidf_fast(accL[r][2]); hr = sigmoidf_fast(accR[r][2]);
            av.z = hl * hr; bv.z = 1.0f - hl;
            hl = sigmoidf_fast(accL[r][3]); hr = sigmoidf_fast(accR[r][3]);
            av.w = hl * hr; bv.w = 1.0f - hl;
            *(float4*)&as_[(r0 + r) * ABP + jL] = av;
            *(float4*)&bs_[(r0 + r) * ABP + jL] = bv;
            // pack to half2 and store to global (a low, b high)
            union { uint4 v; __half2 h[4]; } pk;
            pk.h[0] = __halves2half2(__float2half_rn(av.x), __float2half_rn(bv.x));
            pk.h[1] = __halves2half2(__float2half_rn(av.y), __float2half_rn(bv.y));
            pk.h[2] = __halves2half2(__float2half_rn(av.z), __float2half_rn(bv.z));
            pk.h[3] = __halves2half2(__float2half_rn(av.w), __float2half_rn(bv.w));
            *(uint4*)&ab[(row0 + r0 + r) * 64 + jL] = pk.v;
        }
        __syncthreads();   // B2

        // parallel segment composition: 4 segs x 8 rows
        float A = 1.0f, B = 0.0f;
        const int t0 = seg * 8;
        #pragma unroll
        for (int t = 0; t < 8; ++t) {
            const float a = as_[(t0 + t) * ABP + ch];
            const float b = bs_[(t0 + t) * ABP + ch];
            B = fmaf(a, B, b); A *= a;
        }
        segA[seg * SEGP + ch] = A;
        segB[seg * SEGP + ch] = B;
        __syncthreads();   // B3

        if (tid < 64) {
            #pragma unroll
            for (int q = 0; q < 4; ++q) {
                const float A2 = segA[q * SEGP + tid];
                const float B2v = segB[q * SEGP + tid];
                sB = fmaf(A2, sB, B2v); sA *= A2;
            }
        }
    }

    if (tid < 64) { Aout[c * 64 + tid] = sA; Bout[c * 64 + tid] = sB; }
}

// ============================================================================
// Phase 2: read a,b (half2), scan with carry via parallel segments, emit z,
//          fused out = z@W2 + B2.
// ============================================================================
__global__ __launch_bounds__(256, 3)
void phase2(const __half2* __restrict__ ab, const float* __restrict__ W2,
            const float* __restrict__ B2, const float* __restrict__ carry,
            float* __restrict__ out)
{
    __shared__ __align__(16) __half2 absh[R2 * 64];   // 16 KB
    __shared__ float Zs[R2 * ZP];                     // 16.6 KB
    __shared__ __align__(16) float W2s[64 * W2P];     // 9.2 KB
    __shared__ float B2s[32];
    __shared__ float segA[4 * SEGP];
    __shared__ float segB[4 * SEGP];
    __shared__ float ucur[64];

    const int tid = threadIdx.x;
    const int c   = blockIdx.x;

    for (int i = tid; i < 64 * 32; i += 256) {
        int k = i >> 5, j = i & 31;
        W2s[k * W2P + j] = W2[i];
    }
    if (tid < 32) B2s[tid] = B2[tid];
    if (tid < 64) ucur[tid] = carry[c * 64 + tid];

    const int ch = tid & 63, seg = tid >> 6;          // seg wave-uniform
    const int orow = tid >> 3, oj = (tid & 7) * 4;
    const size_t base = (size_t)c * CHUNK;

    for (int s = 0; s < NS2; ++s) {
        const size_t row0 = base + (size_t)s * R2;

        // stage 64x64 half2 = 1024 uint4
        {
            const uint4* g = (const uint4*)(ab + row0 * 64);
            uint4* l = (uint4*)absh;
            l[tid]       = g[tid];
            l[tid + 256] = g[tid + 256];
            l[tid + 512] = g[tid + 512];
            l[tid + 768] = g[tid + 768];
        }
        __syncthreads();   // B1

        // segment composition: 4 segs x 16 rows
        float A = 1.0f, B = 0.0f;
        const int t0 = seg * 16;
        #pragma unroll
        for (int t = 0; t < 16; ++t) {
            const float2 f = __half22float2(absh[(t0 + t) * 64 + ch]);
            B = fmaf(f.x, B, f.y); A *= f.x;
        }
        segA[seg * SEGP + ch] = A;
        segB[seg * SEGP + ch] = B;
        __syncthreads();   // B2

        // seg-start u, then re-walk emitting z
        float u = ucur[ch];
        #pragma unroll
        for (int q = 0; q < 3; ++q)
            if (q < seg) u = fmaf(segA[q * SEGP + ch], u, segB[q * SEGP + ch]);
        #pragma unroll
        for (int t = 0; t < 16; ++t) {
            const float2 f = __half22float2(absh[(t0 + t) * 64 + ch]);
            Zs[(t0 + t) * ZP + ch] = u;
            u = fmaf(f.x, u, f.y);
        }
        __syncthreads();   // B3

        if (seg == 3) ucur[ch] = u;

        // out = Z @ W2 + B2 : rows orow and orow+32
        float acc0[4], acc1[4];
        #pragma unroll
        for (int i = 0; i < 4; ++i) { acc0[i] = B2s[oj + i]; acc1[i] = B2s[oj + i]; }
        #pragma unroll 4
        for (int k = 0; k < 64; ++k) {
            const float z0 = Zs[orow * ZP + k];
            const float z1 = Zs[(orow + 32) * ZP + k];
            const float4 w = *(const float4*)&W2s[k * W2P + oj];
            acc0[0] += z0 * w.x; acc0[1] += z0 * w.y;
            acc0[2] += z0 * w.z; acc0[3] += z0 * w.w;
            acc1[0] += z1 * w.x; acc1[1] += z1 * w.y;
            acc1[2] += z1 * w.z; acc1[3] += z1 * w.w;
        }
        *(float4*)&out[(row0 + orow) * 32 + oj] =
            make_float4(acc0[0], acc0[1], acc0[2], acc0[3]);
        *(float4*)&out[(row0 + orow + 32) * 32 + oj] =
            make_float4(acc1[0], acc1[1], acc1[2], acc1[3]);
        __syncthreads();   // B4 (protects ucur/Zs/absh for next subtile)
    }
}

// ============================================================================
// Carry scan across 1024 chunk maps: 4 parallel segments of 256.
// carry[c] = composition of chunks < c applied to 0.
// ============================================================================
__global__ void carry_scan(const float* __restrict__ Aar, const float* __restrict__ Bar,
                           float* __restrict__ carry)
{
    __shared__ float sA[4 * SEGP], sB[4 * SEGP];
    const int tid = threadIdx.x;
    const int ch = tid & 63, seg = tid >> 6;
    const int c0 = seg * (NCH / 4);

    float A = 1.0f, B = 0.0f;
    #pragma unroll 8
    for (int i = 0; i < NCH / 4; ++i) {
        const int idx = c0 + i;
        const float a = Aar[idx * 64 + ch];
        const float b = Bar[idx * 64 + ch];
        B = fmaf(a, B, b); A *= a;
    }
    sA[seg * SEGP + ch] = A;
    sB[seg * SEGP + ch] = B;
    __syncthreads();

    float u = 0.0f;
    #pragma unroll
    for (int q = 0; q < 3; ++q)
        if (q < seg) u = fmaf(sA[q * SEGP + ch], u, sB[q * SEGP + ch]);
    #pragma unroll 8
    for (int i = 0; i < NCH / 4; ++i) {
        const int idx = c0 + i;
        carry[idx * 64 + ch] = u;
        u = fmaf(Aar[idx * 64 + ch], u, Bar[idx * 64 + ch]);
    }
}

// ============================================================================
// Fallback (round-0 proven path) if ws_size is too small for the ab buffer.
// ============================================================================
template <bool EMIT>
__global__ __launch_bounds__(256, 2)
void deductron_fallback(const float* __restrict__ x, const float* __restrict__ W1,
                        const float* __restrict__ B1, const float* __restrict__ W2,
                        const float* __restrict__ B2, const float* __restrict__ carry,
                        float* __restrict__ Aout, float* __restrict__ Bout,
                        float* __restrict__ out)
{
    __shared__ __align__(16) float W1s[64 * W1P];
    __shared__ float B1s[128];
    __shared__ float Xs[RSUB * XP];
    __shared__ __align__(16) float as_[RSUB * ABP];
    __shared__ __align__(16) float bs_[RSUB * ABP];
    __shared__ float Zs2[RSUB * ABP];
    __shared__ __align__(16) float W2s[64 * W2P];
    __shared__ float B2s[32];

    const int tid = threadIdx.x;
    const int c   = blockIdx.x;

    for (int i = tid; i < 64 * 128; i += 256) {
        int k = i >> 7, j = i & 127;
        W1s[k * W1P + j] = W1[i];
    }
    if (tid < 128) B1s[tid] = B1[tid];
    if (EMIT) {
        for (int i = tid; i < 64 * 32; i += 256) {
            int k = i >> 5, j = i & 31;
            W2s[k * W2P + j] = W2[i];
        }
        if (tid < 32) B2s[tid] = B2[tid];
    }
    __syncthreads();

    const int ty = tid >> 4, tx = tid & 15;
    const int r0 = ty * 2, jL = tx * 4, jR = 64 + tx * 4;
    float sA = 1.0f, sB = 0.0f, u = 0.0f;
    if (EMIT && tid < 64) u = carry[c * 64 + tid];

    const size_t base = (size_t)c * CHUNK;
    for (int s = 0; s < NSUB; ++s) {
        const size_t row0 = base + (size_t)s * RSUB;
        for (int i = tid; i < RSUB * 64; i += 256) {
            int r = i >> 6, k = i & 63;
            Xs[r * XP + k] = x[row0 * 64 + i];
        }
        __syncthreads();
        float accL[2][4], accR[2][4];
        #pragma unroll
        for (int i = 0; i < 4; ++i) {
            accL[0][i] = B1s[jL + i]; accL[1][i] = B1s[jL + i];
            accR[0][i] = B1s[jR + i]; accR[1][i] = B1s[jR + i];
        }
        #pragma unroll 4
        for (int k = 0; k < 64; ++k) {
            const float x0 = Xs[r0 * XP + k];
            const float x1 = Xs[(r0 + 1) * XP + k];
            const float4 wl = *(const float4*)&W1s[k * W1P + jL];
            const float4 wr = *(const float4*)&W1s[k * W1P + jR];
            accL[0][0] += x0 * wl.x; accL[0][1] += x0 * wl.y;
            accL[0][2] += x0 * wl.z; accL[0][3] += x0 * wl.w;
            accL[1][0] += x1 * wl.x; accL[1][1] += x1 * wl.y;
            accL[1][2] += x1 * wl.z; accL[1][3] += x1 * wl.w;
            accR[0][0] += x0 * wr.x; accR[0][1] += x0 * wr.y;
            accR[0][2] += x0 * wr.z; accR[0][3] += x0 * wr.w;
            accR[1][0] += x1 * wr.x; accR[1][1] += x1 * wr.y;
            accR[1][2] += x1 * wr.z; accR[1][3] += x1 * wr.w;
        }
        #pragma unroll
        for (int r = 0; r < 2; ++r) {
            float4 av, bv; float hl, hr;
            hl = sigmoidf_fast(accL[r][0]); hr = sigmoidf_fast(accR[r][0]);
            av.x = hl * hr; bv.x = 1.0f - hl;
            hl = sigmoidf_fast(accL[r][1]); hr = sigmoidf_fast(accR[r][1]);
            av.y = hl * hr; bv.y = 1.0f - hl;
            hl = sigmoidf_fast(accL[r][2]); hr = sigmoidf_fast(accR[r][2]);
            av.z = hl * hr; bv.z = 1.0f - hl;
            hl = sigmoidf_fast(accL[r][3]); hr = sigmoidf_fast(accR[r][3]);
            av.w = hl * hr; bv.w = 1.0f - hl;
            *(float4*)&as_[(r0 + r) * ABP + jL] = av;
            *(float4*)&bs_[(r0 + r) * ABP + jL] = bv;
        }
        __syncthreads();
        if (tid < 64) {
            #pragma unroll
            for (int t = 0; t < RSUB; ++t) {
                const float at = as_[t * ABP + tid];
                const float bt = bs_[t * ABP + tid];
                if (EMIT) { Zs2[t * ABP + tid] = u; u = fmaf(at, u, bt); }
                else      { sB = fmaf(at, sB, bt); sA *= at; }
            }
        }
        __syncthreads();
        if (EMIT) {
            const int orow = tid >> 3, oj = (tid & 7) * 4;
            float acc[4];
            #pragma unroll
            for (int i = 0; i < 4; ++i) acc[i] = B2s[oj + i];
            #pragma unroll 4
            for (int k = 0; k < 64; ++k) {
                const float z = Zs2[orow * ABP + k];
                const float4 w = *(const float4*)&W2s[k * W2P + oj];
                acc[0] += z * w.x; acc[1] += z * w.y;
                acc[2] += z * w.z; acc[3] += z * w.w;
            }
            *(float4*)&out[(row0 + orow) * 32 + oj] =
                make_float4(acc[0], acc[1], acc[2], acc[3]);
            __syncthreads();
        }
    }
    if (!EMIT && tid < 64) { Aout[c * 64 + tid] = sA; Bout[c * 64 + tid] = sB; }
}

extern "C" void kernel_launch(void* const* d_in, const int* in_sizes, int n_in,
                              void* d_out, int out_size, void* d_ws, size_t ws_size,
                              hipStream_t stream)
{
    const float* x  = (const float*)d_in[0];
    const float* W1 = (const float*)d_in[1];
    const float* B1 = (const float*)d_in[2];
    const float* W2 = (const float*)d_in[3];
    const float* B2 = (const float*)d_in[4];
    float* out = (float*)d_out;

    float* Aar   = (float*)d_ws;            // NCH*64
    float* Bar   = Aar + NCH * 64;          // NCH*64
    float* carry = Bar + NCH * 64;          // NCH*64
    __half2* ab  = (__half2*)(carry + NCH * 64);  // TT*64 half2 = 134 MB

    const size_t need = (size_t)3 * NCH * 64 * 4 + (size_t)TT * 64 * 4;
    if (ws_size >= need) {
        phase1<<<NCH, 256, 0, stream>>>(x, W1, B1, ab, Aar, Bar);
        carry_scan<<<1, 256, 0, stream>>>(Aar, Bar, carry);
        phase2<<<NCH, 256, 0, stream>>>(ab, W2, B2, carry, out);
    } else {
        deductron_fallback<false><<<NCH, 256, 0, stream>>>(x, W1, B1, W2, B2, nullptr,
                                                           Aar, Bar, nullptr);
        carry_scan<<<1, 256, 0, stream>>>(Aar, Bar, carry);
        deductron_fallback<true><<<NCH, 256, 0, stream>>>(x, W1, B1, W2, B2, carry,
                                                          nullptr, nullptr, out);
    }
}

// Round 3
// 328.126 us; speedup vs baseline: 2.0564x; 1.5452x over previous
//
#include <hip/hip_runtime.h>

#define TT    524288
#define CHUNK 512
#define NCH   (TT / CHUNK)     // 1024 chunks
#define SUB   64               // subtile rows
#define NSUB  (CHUNK / SUB)    // 8

typedef __attribute__((ext_vector_type(8))) short short8;
typedef __attribute__((ext_vector_type(4))) float f32x4;

__device__ __forceinline__ unsigned short f2bf(float f) {
    union { float f; unsigned u; } v; v.f = f;
    unsigned r = v.u + 0x7FFFu + ((v.u >> 16) & 1u);   // RTNE
    return (unsigned short)(r >> 16);
}
__device__ __forceinline__ float sigf(float v) {
    return 1.0f / (1.0f + __expf(-v));
}

// ============================================================================
// Unified phase kernel. One block = one chunk of 512 rows, 8 subtiles of 64.
// h = sigmoid(X@W1+B1) via bf16 MFMA; a=l*r, b=1-l; segmented scan in LDS.
// EMIT=false: emit per-chunk affine map (A,B).
// EMIT=true : scan from carry, z@W2+B2 via bf16 MFMA, store out.
// ============================================================================
template <bool EMIT>
__global__ __launch_bounds__(256, 2)
void dphase(const float* __restrict__ x, const float* __restrict__ W1,
            const float* __restrict__ B1, const float* __restrict__ W2,
            const float* __restrict__ B2, const float* __restrict__ carry,
            float* __restrict__ Aout, float* __restrict__ Bout,
            float* __restrict__ out)
{
    __shared__ __align__(16) short  W1t[128 * 72];   // W1^T bf16 [n][k]
    __shared__ float  B1s[128];
    __shared__ __align__(16) short  Xs[SUB * 72];    // X bf16 [m][k]
    __shared__ __align__(16) float2 abf[SUB * 66];   // (a,b) fp32 [m][ch]
    __shared__ float  segA[4 * 66], segB[4 * 66];
    __shared__ float  ucur[64];
    __shared__ __align__(16) short  W2t[32 * 72];    // W2^T bf16 [n][k]
    __shared__ float  B2s[32];
    __shared__ __align__(16) short  Zs[SUB * 72];    // z bf16 [m][k]

    const int tid  = threadIdx.x;
    const int c    = blockIdx.x;
    const int wave = tid >> 6;
    const int lane = tid & 63;
    const int quad = lane >> 4;
    const int lr   = lane & 15;

    // ---- stage W1^T (bf16), biases, (W2^T, carry) ----
    for (int i = tid; i < 2048; i += 256) {
        float4 w4 = ((const float4*)W1)[i];
        int k = i >> 5, n0 = (i & 31) * 4;
        W1t[(n0 + 0) * 72 + k] = (short)f2bf(w4.x);
        W1t[(n0 + 1) * 72 + k] = (short)f2bf(w4.y);
        W1t[(n0 + 2) * 72 + k] = (short)f2bf(w4.z);
        W1t[(n0 + 3) * 72 + k] = (short)f2bf(w4.w);
    }
    if (tid < 128) B1s[tid] = B1[tid];
    if (EMIT) {
        for (int i = tid; i < 512; i += 256) {
            float4 w4 = ((const float4*)W2)[i];
            int k = i >> 3, n0 = (i & 7) * 4;
            W2t[(n0 + 0) * 72 + k] = (short)f2bf(w4.x);
            W2t[(n0 + 1) * 72 + k] = (short)f2bf(w4.y);
            W2t[(n0 + 2) * 72 + k] = (short)f2bf(w4.z);
            W2t[(n0 + 3) * 72 + k] = (short)f2bf(w4.w);
        }
        if (tid < 32) B2s[tid] = B2[tid];
        if (tid < 64) ucur[tid] = carry[c * 64 + tid];
    }

    const float4* xg = (const float4*)(x + (size_t)c * CHUNK * 64);
    float4 xr0 = xg[tid], xr1 = xg[tid + 256], xr2 = xg[tid + 512], xr3 = xg[tid + 768];

    float sA = 1.0f, sB = 0.0f;   // !EMIT running chunk map (tid<64)

    for (int s = 0; s < NSUB; ++s) {
        // ---- write prefetched subtile to LDS as bf16 ----
        {
            float4 v; int f;
#define PUTX(R, J) { v = (R); f = tid + 256 * (J); int row = f >> 4, c4 = (f & 15) * 4; \
            unsigned lo = (unsigned)f2bf(v.x) | ((unsigned)f2bf(v.y) << 16); \
            unsigned hi = (unsigned)f2bf(v.z) | ((unsigned)f2bf(v.w) << 16); \
            *(uint2*)&Xs[row * 72 + c4] = make_uint2(lo, hi); }
            PUTX(xr0, 0) PUTX(xr1, 1) PUTX(xr2, 2) PUTX(xr3, 3)
#undef PUTX
        }
        __syncthreads();   // A: Xs (and, first iter, W1t/W2t/ucur) visible

        if (s + 1 < NSUB) {   // prefetch next subtile (overlaps compute)
            const float4* xn = xg + (size_t)(s + 1) * 1024;
            xr0 = xn[tid]; xr1 = xn[tid + 256]; xr2 = xn[tid + 512]; xr3 = xn[tid + 768];
        }

        // ---- MFMA: wave w owns rows w*16..w*16+15, all 8 col-tiles ----
        f32x4 acc[8];
        #pragma unroll
        for (int j = 0; j < 8; ++j) {
            float b = B1s[j * 16 + lr];
            acc[j][0] = b; acc[j][1] = b; acc[j][2] = b; acc[j][3] = b;
        }
        const short8 a0 = *(const short8*)&Xs[(wave * 16 + lr) * 72 + quad * 8];
        const short8 a1 = *(const short8*)&Xs[(wave * 16 + lr) * 72 + quad * 8 + 32];
        #pragma unroll
        for (int j = 0; j < 8; ++j) {
            const short8 b0 = *(const short8*)&W1t[(j * 16 + lr) * 72 + quad * 8];
            const short8 b1 = *(const short8*)&W1t[(j * 16 + lr) * 72 + quad * 8 + 32];
            acc[j] = __builtin_amdgcn_mfma_f32_16x16x32_bf16(a0, b0, acc[j], 0, 0, 0);
            acc[j] = __builtin_amdgcn_mfma_f32_16x16x32_bf16(a1, b1, acc[j], 0, 0, 0);
        }

        // ---- sigmoid; a = l*r, b = 1-l; transpose to [row][ch] in LDS ----
        #pragma unroll
        for (int j = 0; j < 4; ++j) {
            #pragma unroll
            for (int r = 0; r < 4; ++r) {
                float hl = sigf(acc[j][r]);
                float hr = sigf(acc[j + 4][r]);
                int m = wave * 16 + quad * 4 + r;
                abf[m * 66 + j * 16 + lr] = make_float2(hl * hr, 1.0f - hl);
            }
        }
        __syncthreads();   // B

        // ---- segmented composition: wave w composes rows w*16..+15 ----
        float A = 1.0f, Bv = 0.0f;
        #pragma unroll
        for (int t = 0; t < 16; ++t) {
            float2 f2 = abf[(wave * 16 + t) * 66 + lane];
            Bv = fmaf(f2.x, Bv, f2.y); A *= f2.x;
        }
        segA[wave * 66 + lane] = A;
        segB[wave * 66 + lane] = Bv;
        __syncthreads();   // C

        if (EMIT) {
            float u = ucur[lane];
            #pragma unroll
            for (int q = 0; q < 3; ++q)
                if (q < wave) u = fmaf(segA[q * 66 + lane], u, segB[q * 66 + lane]);
            #pragma unroll
            for (int t = 0; t < 16; ++t) {
                float2 f2 = abf[(wave * 16 + t) * 66 + lane];
                Zs[(wave * 16 + t) * 72 + lane] = (short)f2bf(u);  // z BEFORE map
                u = fmaf(f2.x, u, f2.y);
            }
            const float unew = u;
            __syncthreads();   // D: Zs complete
            if (wave == 3) ucur[lane] = unew;   // next read is after next sync C

            // ---- out = Z @ W2 + B2 via MFMA, fused store ----
            const short8 za0 = *(const short8*)&Zs[(wave * 16 + lr) * 72 + quad * 8];
            const short8 za1 = *(const short8*)&Zs[(wave * 16 + lr) * 72 + quad * 8 + 32];
            const size_t row0g = (size_t)c * CHUNK + (size_t)s * SUB;
            #pragma unroll
            for (int nt = 0; nt < 2; ++nt) {
                f32x4 cc;
                float b = B2s[nt * 16 + lr];
                cc[0] = b; cc[1] = b; cc[2] = b; cc[3] = b;
                const short8 b0 = *(const short8*)&W2t[(nt * 16 + lr) * 72 + quad * 8];
                const short8 b1 = *(const short8*)&W2t[(nt * 16 + lr) * 72 + quad * 8 + 32];
                cc = __builtin_amdgcn_mfma_f32_16x16x32_bf16(za0, b0, cc, 0, 0, 0);
                cc = __builtin_amdgcn_mfma_f32_16x16x32_bf16(za1, b1, cc, 0, 0, 0);
                #pragma unroll
                for (int r = 0; r < 4; ++r) {
                    int m = wave * 16 + quad * 4 + r;
                    out[(row0g + m) * 32 + nt * 16 + lr] = cc[r];
                }
            }
        } else {
            if (tid < 64) {
                #pragma unroll
                for (int q = 0; q < 4; ++q) {
                    float A2 = segA[q * 66 + tid], B2v = segB[q * 66 + tid];
                    sB = fmaf(A2, sB, B2v); sA *= A2;
                }
            }
        }
    }

    if (!EMIT && tid < 64) { Aout[c * 64 + tid] = sA; Bout[c * 64 + tid] = sB; }
}

// ============================================================================
// Carry scan across 1024 chunk maps: 8 parallel segments of 128 (512 thr).
// ============================================================================
__global__ void carry_scan(const float* __restrict__ Aar, const float* __restrict__ Bar,
                           float* __restrict__ carry)
{
    __shared__ float sA[8 * 66], sB[8 * 66];
    const int tid = threadIdx.x;
    const int ch = tid & 63, seg = tid >> 6;       // 8 segments
    const int c0 = seg * (NCH / 8);

    float A = 1.0f, B = 0.0f;
    #pragma unroll 8
    for (int i = 0; i < NCH / 8; ++i) {
        const int idx = c0 + i;
        const float a = Aar[idx * 64 + ch];
        const float b = Bar[idx * 64 + ch];
        B = fmaf(a, B, b); A *= a;
    }
    sA[seg * 66 + ch] = A;
    sB[seg * 66 + ch] = B;
    __syncthreads();

    float u = 0.0f;
    #pragma unroll
    for (int q = 0; q < 7; ++q)
        if (q < seg) u = fmaf(sA[q * 66 + ch], u, sB[q * 66 + ch]);
    #pragma unroll 8
    for (int i = 0; i < NCH / 8; ++i) {
        const int idx = c0 + i;
        carry[idx * 64 + ch] = u;
        u = fmaf(Aar[idx * 64 + ch], u, Bar[idx * 64 + ch]);
    }
}

extern "C" void kernel_launch(void* const* d_in, const int* in_sizes, int n_in,
                              void* d_out, int out_size, void* d_ws, size_t ws_size,
                              hipStream_t stream)
{
    const float* x  = (const float*)d_in[0];
    const float* W1 = (const float*)d_in[1];
    const float* B1 = (const float*)d_in[2];
    const float* W2 = (const float*)d_in[3];
    const float* B2 = (const float*)d_in[4];
    float* out = (float*)d_out;

    float* Aar   = (float*)d_ws;            // NCH*64
    float* Bar   = Aar + NCH * 64;          // NCH*64
    float* carry = Bar + NCH * 64;          // NCH*64  (total 768 KB)

    dphase<false><<<NCH, 256, 0, stream>>>(x, W1, B1, W2, B2, nullptr,
                                           Aar, Bar, nullptr);
    carry_scan<<<1, 512, 0, stream>>>(Aar, Bar, carry);
    dphase<true><<<NCH, 256, 0, stream>>>(x, W1, B1, W2, B2, carry,
                                          nullptr, nullptr, out);
}

// Round 4
// 301.514 us; speedup vs baseline: 2.2379x; 1.0883x over previous
//
#include <hip/hip_runtime.h>

#define TT    524288
#define CHUNK 512
#define NCH   (TT / CHUNK)     // 1024 chunks
#define SUB   64               // subtile rows
#define NSUB  (CHUNK / SUB)    // 8

typedef __attribute__((ext_vector_type(8))) short short8;
typedef __attribute__((ext_vector_type(4))) float f32x4;

__device__ __forceinline__ unsigned short f2bf(float f) {
    union { float f; unsigned u; } v; v.f = f;
    unsigned r = v.u + 0x7FFFu + ((v.u >> 16) & 1u);   // RTNE
    return (unsigned short)(r >> 16);
}
// pack (a,b) -> bf16(a) | bf16(b)<<16
__device__ __forceinline__ unsigned packbf2(float a, float b) {
    union { float f; unsigned u; } va, vb; va.f = a; vb.f = b;
    unsigned ra = va.u + 0x7FFFu + ((va.u >> 16) & 1u);
    unsigned rb = vb.u + 0x7FFFu + ((vb.u >> 16) & 1u);
    return (ra >> 16) | (rb & 0xFFFF0000u);
}
__device__ __forceinline__ float2 unpackbf2(unsigned w) {
    union { unsigned u; float f; } a, b;
    a.u = w << 16; b.u = w & 0xFFFF0000u;
    return make_float2(a.f, b.f);
}
__device__ __forceinline__ float sigf(float v) {
    return __builtin_amdgcn_rcpf(1.0f + __expf(-v));   // v_exp + v_rcp
}

// ============================================================================
// One block = one chunk of 512 rows, 8 subtiles of 64.
// h = sigmoid(X@W1+B1) via bf16 MFMA; a=l*r, b=1-l packed bf16x2 in LDS;
// 4-wave segmented scan. EMIT=false -> chunk map (A,B); EMIT=true -> z, out.
// LDS = 51.9 KB -> 3 blocks/CU.
// ============================================================================
template <bool EMIT>
__global__ __launch_bounds__(256, 3)
void dphase(const float* __restrict__ x, const float* __restrict__ W1,
            const float* __restrict__ B1, const float* __restrict__ W2,
            const float* __restrict__ B2, const float* __restrict__ carry,
            float* __restrict__ Aout, float* __restrict__ Bout,
            float* __restrict__ out)
{
    __shared__ __align__(16) short    W1t[128 * 72];  // W1^T bf16 [n][k] 18.4KB
    __shared__ float    B1s[128];
    __shared__ __align__(16) short    XZ[SUB * 72];   // X bf16 [m][k]; reused as Z
    __shared__ unsigned abp[SUB * 65];                // packed (a,b) [m][ch] 16.6KB
    __shared__ float    segA[4 * 66], segB[4 * 66];
    __shared__ float    ucur[64];
    __shared__ __align__(16) short    W2t[32 * 72];   // W2^T bf16 [n][k]
    __shared__ float    B2s[32];

    const int tid  = threadIdx.x;
    const int c    = blockIdx.x;
    const int wave = tid >> 6;
    const int lane = tid & 63;
    const int quad = lane >> 4;
    const int lr   = lane & 15;

    for (int i = tid; i < 2048; i += 256) {
        float4 w4 = ((const float4*)W1)[i];
        int k = i >> 5, n0 = (i & 31) * 4;
        W1t[(n0 + 0) * 72 + k] = (short)f2bf(w4.x);
        W1t[(n0 + 1) * 72 + k] = (short)f2bf(w4.y);
        W1t[(n0 + 2) * 72 + k] = (short)f2bf(w4.z);
        W1t[(n0 + 3) * 72 + k] = (short)f2bf(w4.w);
    }
    if (tid < 128) B1s[tid] = B1[tid];
    if (EMIT) {
        for (int i = tid; i < 512; i += 256) {
            float4 w4 = ((const float4*)W2)[i];
            int k = i >> 3, n0 = (i & 7) * 4;
            W2t[(n0 + 0) * 72 + k] = (short)f2bf(w4.x);
            W2t[(n0 + 1) * 72 + k] = (short)f2bf(w4.y);
            W2t[(n0 + 2) * 72 + k] = (short)f2bf(w4.z);
            W2t[(n0 + 3) * 72 + k] = (short)f2bf(w4.w);
        }
        if (tid < 32) B2s[tid] = B2[tid];
        if (tid < 64) ucur[tid] = carry[c * 64 + tid];
    }

    const float4* xg = (const float4*)(x + (size_t)c * CHUNK * 64);
    float4 xr0 = xg[tid], xr1 = xg[tid + 256], xr2 = xg[tid + 512], xr3 = xg[tid + 768];

    float sA = 1.0f, sB = 0.0f;   // !EMIT running chunk map (tid<64)

    for (int s = 0; s < NSUB; ++s) {
        // ---- write prefetched subtile to LDS as bf16 ----
        {
            float4 v; int f;
#define PUTX(R, J) { v = (R); f = tid + 256 * (J); int row = f >> 4, c4 = (f & 15) * 4; \
            unsigned lo = (unsigned)f2bf(v.x) | ((unsigned)f2bf(v.y) << 16); \
            unsigned hi = (unsigned)f2bf(v.z) | ((unsigned)f2bf(v.w) << 16); \
            *(uint2*)&XZ[row * 72 + c4] = make_uint2(lo, hi); }
            PUTX(xr0, 0) PUTX(xr1, 1) PUTX(xr2, 2) PUTX(xr3, 3)
#undef PUTX
        }
        __syncthreads();   // A

        if (s + 1 < NSUB) {
            const float4* xn = xg + (size_t)(s + 1) * 1024;
            xr0 = xn[tid]; xr1 = xn[tid + 256]; xr2 = xn[tid + 512]; xr3 = xn[tid + 768];
        }

        // ---- MFMA: wave w owns rows w*16..+15, all 8 col-tiles ----
        f32x4 acc[8];
        #pragma unroll
        for (int j = 0; j < 8; ++j) {
            float b = B1s[j * 16 + lr];
            acc[j][0] = b; acc[j][1] = b; acc[j][2] = b; acc[j][3] = b;
        }
        const short8 a0 = *(const short8*)&XZ[(wave * 16 + lr) * 72 + quad * 8];
        const short8 a1 = *(const short8*)&XZ[(wave * 16 + lr) * 72 + quad * 8 + 32];
        #pragma unroll
        for (int j = 0; j < 8; ++j) {
            const short8 b0 = *(const short8*)&W1t[(j * 16 + lr) * 72 + quad * 8];
            const short8 b1 = *(const short8*)&W1t[(j * 16 + lr) * 72 + quad * 8 + 32];
            acc[j] = __builtin_amdgcn_mfma_f32_16x16x32_bf16(a0, b0, acc[j], 0, 0, 0);
            acc[j] = __builtin_amdgcn_mfma_f32_16x16x32_bf16(a1, b1, acc[j], 0, 0, 0);
        }

        // ---- sigmoid; a=l*r, b=1-l; pack bf16x2 -> abp[m][ch] ----
        #pragma unroll
        for (int j = 0; j < 4; ++j) {
            #pragma unroll
            for (int r = 0; r < 4; ++r) {
                float hl = sigf(acc[j][r]);
                float hr = sigf(acc[j + 4][r]);
                int m = wave * 16 + quad * 4 + r;
                abp[m * 65 + j * 16 + lr] = packbf2(hl * hr, 1.0f - hl);
            }
        }
        __syncthreads();   // B

        // ---- segmented composition: wave w composes its 16 rows ----
        float A = 1.0f, Bv = 0.0f;
        #pragma unroll
        for (int t = 0; t < 16; ++t) {
            float2 f2 = unpackbf2(abp[(wave * 16 + t) * 65 + lane]);
            Bv = fmaf(f2.x, Bv, f2.y); A *= f2.x;
        }
        segA[wave * 66 + lane] = A;
        segB[wave * 66 + lane] = Bv;
        __syncthreads();   // C

        if (EMIT) {
            float u = ucur[lane];
            #pragma unroll
            for (int q = 0; q < 3; ++q)
                if (q < wave) u = fmaf(segA[q * 66 + lane], u, segB[q * 66 + lane]);
            // emit z into XZ (each wave touches only its own 16-row band)
            #pragma unroll
            for (int t = 0; t < 16; ++t) {
                float2 f2 = unpackbf2(abp[(wave * 16 + t) * 65 + lane]);
                XZ[(wave * 16 + t) * 72 + lane] = (short)f2bf(u);
                u = fmaf(f2.x, u, f2.y);
            }
            if (wave == 3) ucur[lane] = u;   // next read is after next sync C

            // ---- out = Z @ W2 + B2 via MFMA (reads own band only) ----
            const short8 za0 = *(const short8*)&XZ[(wave * 16 + lr) * 72 + quad * 8];
            const short8 za1 = *(const short8*)&XZ[(wave * 16 + lr) * 72 + quad * 8 + 32];
            const size_t row0g = (size_t)c * CHUNK + (size_t)s * SUB;
            #pragma unroll
            for (int nt = 0; nt < 2; ++nt) {
                f32x4 cc;
                float b = B2s[nt * 16 + lr];
                cc[0] = b; cc[1] = b; cc[2] = b; cc[3] = b;
                const short8 b0 = *(const short8*)&W2t[(nt * 16 + lr) * 72 + quad * 8];
                const short8 b1 = *(const short8*)&W2t[(nt * 16 + lr) * 72 + quad * 8 + 32];
                cc = __builtin_amdgcn_mfma_f32_16x16x32_bf16(za0, b0, cc, 0, 0, 0);
                cc = __builtin_amdgcn_mfma_f32_16x16x32_bf16(za1, b1, cc, 0, 0, 0);
                #pragma unroll
                for (int r = 0; r < 4; ++r) {
                    int m = wave * 16 + quad * 4 + r;
                    out[(row0g + m) * 32 + nt * 16 + lr] = cc[r];
                }
            }
            __syncthreads();   // E: XZ/abp fully consumed before next PUTX
        } else {
            if (tid < 64) {
                #pragma unroll
                for (int q = 0; q < 4; ++q) {
                    float A2 = segA[q * 66 + tid], B2v = segB[q * 66 + tid];
                    sB = fmaf(A2, sB, B2v); sA *= A2;
                }
            }
        }
    }

    if (!EMIT && tid < 64) { Aout[c * 64 + tid] = sA; Bout[c * 64 + tid] = sB; }
}

// ============================================================================
// Carry scan across 1024 chunk maps: 16 parallel segments of 64 (1024 thr).
// ============================================================================
__global__ void carry_scan(const float* __restrict__ Aar, const float* __restrict__ Bar,
                           float* __restrict__ carry)
{
    __shared__ float sA[16 * 66], sB[16 * 66];
    const int tid = threadIdx.x;
    const int ch = tid & 63, seg = tid >> 6;       // 16 segments
    const int c0 = seg * (NCH / 16);

    float A = 1.0f, B = 0.0f;
    #pragma unroll 8
    for (int i = 0; i < NCH / 16; ++i) {
        const int idx = c0 + i;
        const float a = Aar[idx * 64 + ch];
        const float b = Bar[idx * 64 + ch];
        B = fmaf(a, B, b); A *= a;
    }
    sA[seg * 66 + ch] = A;
    sB[seg * 66 + ch] = B;
    __syncthreads();

    float u = 0.0f;
    #pragma unroll
    for (int q = 0; q < 15; ++q)
        if (q < seg) u = fmaf(sA[q * 66 + ch], u, sB[q * 66 + ch]);
    #pragma unroll 8
    for (int i = 0; i < NCH / 16; ++i) {
        const int idx = c0 + i;
        carry[idx * 64 + ch] = u;
        u = fmaf(Aar[idx * 64 + ch], u, Bar[idx * 64 + ch]);
    }
}

extern "C" void kernel_launch(void* const* d_in, const int* in_sizes, int n_in,
                              void* d_out, int out_size, void* d_ws, size_t ws_size,
                              hipStream_t stream)
{
    const float* x  = (const float*)d_in[0];
    const float* W1 = (const float*)d_in[1];
    const float* B1 = (const float*)d_in[2];
    const float* W2 = (const float*)d_in[3];
    const float* B2 = (const float*)d_in[4];
    float* out = (float*)d_out;

    float* Aar   = (float*)d_ws;            // NCH*64
    float* Bar   = Aar + NCH * 64;          // NCH*64
    float* carry = Bar + NCH * 64;          // NCH*64

    dphase<false><<<NCH, 256, 0, stream>>>(x, W1, B1, W2, B2, nullptr,
                                           Aar, Bar, nullptr);
    carry_scan<<<1, 1024, 0, stream>>>(Aar, Bar, carry);
    dphase<true><<<NCH, 256, 0, stream>>>(x, W1, B1, W2, B2, carry,
                                          nullptr, nullptr, out);
}